// Round 2
// baseline (61.248 us; speedup 1.0000x reference)
//
#include <hip/hip_runtime.h>
#include <math.h>

#define WIN 7
#define WPT 4               // windows per thread in kssim (16B base stride = coalesced)
#define BLK 256
#define TILE (BLK * WPT)    // 1024 windows per block

__device__ __forceinline__ float ssim_from(float sx, float sy, float sxx, float syy,
                                           float sxy, float C1, float C2) {
    const float inv7 = 1.0f / 7.0f;
    const float covn = 7.0f / 6.0f;
    float ux  = sx  * inv7;
    float uy  = sy  * inv7;
    float uxx = sxx * inv7;
    float uyy = syy * inv7;
    float uxy = sxy * inv7;
    float vx  = covn * (uxx - ux * ux);
    float vy  = covn * (uyy - uy * uy);
    float vxy = covn * (uxy - ux * uy);
    float A1 = 2.0f * ux * uy + C1;
    float A2 = 2.0f * vxy + C2;
    float B1 = ux * ux + uy * uy + C1;
    float B2 = vx + vy + C2;
    float num = A1 * A2;
    float den = B1 * B2;
    return num * __builtin_amdgcn_rcpf(den);   // ~1 ulp, fine vs 2% tol
}

__global__ __launch_bounds__(BLK) void kmax_partial(const float* __restrict__ y, int n,
                                                    float* __restrict__ outMax) {
    int tid = blockIdx.x * blockDim.x + threadIdx.x;
    int stride = gridDim.x * blockDim.x;
    int n4 = n >> 2;
    const float4* y4 = (const float4*)y;
    float m = -__builtin_huge_valf();
    for (int i = tid; i < n4; i += stride) {
        float4 v = y4[i];
        m = fmaxf(m, fmaxf(fmaxf(v.x, v.y), fmaxf(v.z, v.w)));
    }
    for (int i = (n4 << 2) + tid; i < n; i += stride) m = fmaxf(m, y[i]);
    #pragma unroll
    for (int off = 32; off; off >>= 1) m = fmaxf(m, __shfl_xor(m, off));
    __shared__ float sm[4];
    if ((threadIdx.x & 63) == 0) sm[threadIdx.x >> 6] = m;
    __syncthreads();
    if (threadIdx.x == 0)
        outMax[blockIdx.x] = fmaxf(fmaxf(sm[0], sm[1]), fmaxf(sm[2], sm[3]));
}

__global__ __launch_bounds__(BLK) void kmax_final(const float* __restrict__ part, int np,
                                                  float* __restrict__ outMax) {
    float m = -__builtin_huge_valf();
    for (int i = threadIdx.x; i < np; i += BLK) m = fmaxf(m, part[i]);
    #pragma unroll
    for (int off = 32; off; off >>= 1) m = fmaxf(m, __shfl_xor(m, off));
    __shared__ float sm[4];
    if ((threadIdx.x & 63) == 0) sm[threadIdx.x >> 6] = m;
    __syncthreads();
    if (threadIdx.x == 0)
        outMax[0] = fmaxf(fmaxf(sm[0], sm[1]), fmaxf(sm[2], sm[3]));
}

__global__ __launch_bounds__(BLK) void kssim(const float* __restrict__ x,
                                             const float* __restrict__ y,
                                             const float* __restrict__ maxPtr, int n,
                                             float* __restrict__ blockSums) {
    const int nw = n - (WIN - 1);
    const int w0 = blockIdx.x * TILE + threadIdx.x * WPT;
    float dr = maxPtr[0];
    float C1 = (0.01f * dr) * (0.01f * dr);
    float C2 = (0.03f * dr) * (0.03f * dr);
    float acc = 0.0f;

    // need floats [w0, w0 + WPT-1 + WIN) = [w0, w0+10); load 12 (3x float4)
    if (w0 + WPT + 8 <= n) {   // fast path: safely read 12 floats from w0
        float xv[WPT + 8], yv[WPT + 8];
        const float4* x4 = (const float4*)(x + w0);  // w0 multiple of 4 -> 16B aligned
        const float4* y4 = (const float4*)(y + w0);
        #pragma unroll
        for (int i = 0; i < (WPT + 8) / 4; i++) {
            float4 a = x4[i];                         // lane-contiguous: fully coalesced
            xv[4*i+0] = a.x; xv[4*i+1] = a.y; xv[4*i+2] = a.z; xv[4*i+3] = a.w;
            float4 b = y4[i];
            yv[4*i+0] = b.x; yv[4*i+1] = b.y; yv[4*i+2] = b.z; yv[4*i+3] = b.w;
        }
        float sx = 0.f, sy = 0.f, sxx = 0.f, syy = 0.f, sxy = 0.f;
        #pragma unroll
        for (int k = 0; k < WIN; k++) {
            float a = xv[k], b = yv[k];
            sx += a; sy += b;
            sxx = fmaf(a, a, sxx);
            syy = fmaf(b, b, syy);
            sxy = fmaf(a, b, sxy);
        }
        #pragma unroll
        for (int j = 0; j < WPT; j++) {
            acc += ssim_from(sx, sy, sxx, syy, sxy, C1, C2);
            if (j < WPT - 1) {
                float ao = xv[j], an = xv[j + WIN];
                float bo = yv[j], bn = yv[j + WIN];
                sx += an - ao;
                sy += bn - bo;
                sxx += fmaf(an, an, -(ao * ao));
                syy += fmaf(bn, bn, -(bo * bo));
                sxy += fmaf(an, bn, -(ao * bo));
            }
        }
    } else {   // tail: scalar, guarded (only the very last thread(s) of the grid)
        for (int j = 0; j < WPT; j++) {
            int w = w0 + j;
            if (w >= nw) break;
            float sx = 0.f, sy = 0.f, sxx = 0.f, syy = 0.f, sxy = 0.f;
            for (int k = 0; k < WIN; k++) {
                float a = x[w + k], b = y[w + k];
                sx += a; sy += b;
                sxx = fmaf(a, a, sxx);
                syy = fmaf(b, b, syy);
                sxy = fmaf(a, b, sxy);
            }
            acc += ssim_from(sx, sy, sxx, syy, sxy, C1, C2);
        }
    }

    #pragma unroll
    for (int off = 32; off; off >>= 1) acc += __shfl_xor(acc, off);
    __shared__ float sm[4];
    if ((threadIdx.x & 63) == 0) sm[threadIdx.x >> 6] = acc;
    __syncthreads();
    if (threadIdx.x == 0)
        blockSums[blockIdx.x] = (sm[0] + sm[1]) + (sm[2] + sm[3]);
}

__global__ __launch_bounds__(BLK) void kfinal(const float* __restrict__ blockSums, int nb,
                                              float* __restrict__ out, int nw) {
    double s = 0.0;
    for (int i = threadIdx.x; i < nb; i += BLK) s += (double)blockSums[i];
    #pragma unroll
    for (int off = 32; off; off >>= 1) s += __shfl_xor(s, off);
    __shared__ double sm[4];
    if ((threadIdx.x & 63) == 0) sm[threadIdx.x >> 6] = s;
    __syncthreads();
    if (threadIdx.x == 0)
        out[0] = (float)(((sm[0] + sm[1]) + (sm[2] + sm[3])) / (double)nw);
}

extern "C" void kernel_launch(void* const* d_in, const int* in_sizes, int n_in,
                              void* d_out, int out_size, void* d_ws, size_t ws_size,
                              hipStream_t stream) {
    const float* x = (const float*)d_in[0];
    const float* y = (const float*)d_in[1];
    float* out = (float*)d_out;
    int n = in_sizes[0];
    int nw = n - (WIN - 1);

    float* wsf = (float*)d_ws;
    float* partMax   = wsf;          // 2048 floats
    float* finalMax  = wsf + 2048;   // 1 float
    float* blockSums = wsf + 4096;   // nblocks floats (16384)

    const int MAXBLOCKS = 2048;
    int nblocks = (nw + TILE - 1) / TILE;

    kmax_partial<<<MAXBLOCKS, BLK, 0, stream>>>(y, n, partMax);
    kmax_final<<<1, BLK, 0, stream>>>(partMax, MAXBLOCKS, finalMax);
    kssim<<<nblocks, BLK, 0, stream>>>(x, y, finalMax, n, blockSums);
    kfinal<<<1, BLK, 0, stream>>>(blockSums, nblocks, out, nw);
}

// Round 3
// 48.575 us; speedup vs baseline: 1.2609x; 1.2609x over previous
//
#include <hip/hip_runtime.h>
#include <math.h>

#define WIN 7
#define WPT 4               // windows per thread (1 float4 of own data per array)
#define BLK 256
#define TILE (BLK * WPT)    // 1024 windows per tile
#define SSIM_BLOCKS 2048
#define MAXBLOCKS 2048

__device__ __forceinline__ float ssim_from(float sx, float sy, float sxx, float syy,
                                           float sxy, float C1, float C2) {
    const float inv7 = 1.0f / 7.0f;
    const float covn = 7.0f / 6.0f;
    float ux  = sx  * inv7;
    float uy  = sy  * inv7;
    float uxx = sxx * inv7;
    float uyy = syy * inv7;
    float uxy = sxy * inv7;
    float vx  = covn * (uxx - ux * ux);
    float vy  = covn * (uyy - uy * uy);
    float vxy = covn * (uxy - ux * uy);
    float A1 = 2.0f * ux * uy + C1;
    float A2 = 2.0f * vxy + C2;
    float B1 = ux * ux + uy * uy + C1;
    float B2 = vx + vy + C2;
    float num = A1 * A2;
    float den = B1 * B2;
    return num * __builtin_amdgcn_rcpf(den);   // ~1 ulp, fine vs 2% tol
}

__global__ __launch_bounds__(BLK) void kmax_partial(const float* __restrict__ y, int n,
                                                    float* __restrict__ outMax) {
    int tid = blockIdx.x * blockDim.x + threadIdx.x;
    int stride = gridDim.x * blockDim.x;
    int n4 = n >> 2;
    const float4* y4 = (const float4*)y;
    float m = -__builtin_huge_valf();
    for (int i = tid; i < n4; i += stride) {
        float4 v = y4[i];
        m = fmaxf(m, fmaxf(fmaxf(v.x, v.y), fmaxf(v.z, v.w)));
    }
    for (int i = (n4 << 2) + tid; i < n; i += stride) m = fmaxf(m, y[i]);
    #pragma unroll
    for (int off = 32; off; off >>= 1) m = fmaxf(m, __shfl_xor(m, off));
    __shared__ float sm[4];
    if ((threadIdx.x & 63) == 0) sm[threadIdx.x >> 6] = m;
    __syncthreads();
    if (threadIdx.x == 0)
        outMax[blockIdx.x] = fmaxf(fmaxf(sm[0], sm[1]), fmaxf(sm[2], sm[3]));
}

__global__ __launch_bounds__(BLK) void kmax_final(const float* __restrict__ part, int np,
                                                  float* __restrict__ outMax) {
    float m = -__builtin_huge_valf();
    for (int i = threadIdx.x; i < np; i += BLK) m = fmaxf(m, part[i]);
    #pragma unroll
    for (int off = 32; off; off >>= 1) m = fmaxf(m, __shfl_xor(m, off));
    __shared__ float sm[4];
    if ((threadIdx.x & 63) == 0) sm[threadIdx.x >> 6] = m;
    __syncthreads();
    if (threadIdx.x == 0)
        outMax[0] = fmaxf(fmaxf(sm[0], sm[1]), fmaxf(sm[2], sm[3]));
}

__global__ __launch_bounds__(BLK) void kssim(const float* __restrict__ x,
                                             const float* __restrict__ y,
                                             const float* __restrict__ maxPtr, int n,
                                             int ntiles,
                                             float* __restrict__ blockSums) {
    const int nw = n - (WIN - 1);
    const int lane = threadIdx.x & 63;
    float dr = maxPtr[0];
    float C1 = (0.01f * dr) * (0.01f * dr);
    float C2 = (0.03f * dr) * (0.03f * dr);
    float acc = 0.0f;

    for (int tb = blockIdx.x; tb < ntiles; tb += gridDim.x) {
        const int T = tb * TILE;
        const int w0 = T + threadIdx.x * WPT;

        if (T + TILE + 8 <= n) {
            // Each thread loads EXACTLY its own 4 floats per array (1x traffic,
            // fully coalesced); the 6-float halo comes from neighbor lanes.
            float4 a = *(const float4*)(x + w0);
            float4 b = *(const float4*)(y + w0);
            float xv[10], yv[10];
            xv[0]=a.x; xv[1]=a.y; xv[2]=a.z; xv[3]=a.w;
            yv[0]=b.x; yv[1]=b.y; yv[2]=b.z; yv[3]=b.w;
            xv[4]=__shfl_down(a.x,1); xv[5]=__shfl_down(a.y,1);
            xv[6]=__shfl_down(a.z,1); xv[7]=__shfl_down(a.w,1);
            xv[8]=__shfl_down(a.x,2); xv[9]=__shfl_down(a.y,2);
            yv[4]=__shfl_down(b.x,1); yv[5]=__shfl_down(b.y,1);
            yv[6]=__shfl_down(b.z,1); yv[7]=__shfl_down(b.w,1);
            yv[8]=__shfl_down(b.x,2); yv[9]=__shfl_down(b.y,2);
            if (lane >= 62) {           // wave-edge halo patch (L1/L2 hits)
                if (lane == 63) {
                    float4 t = *(const float4*)(x + w0 + 4);
                    xv[4]=t.x; xv[5]=t.y; xv[6]=t.z; xv[7]=t.w;
                    float4 u = *(const float4*)(y + w0 + 4);
                    yv[4]=u.x; yv[5]=u.y; yv[6]=u.z; yv[7]=u.w;
                }
                xv[8]=x[w0+8]; xv[9]=x[w0+9];
                yv[8]=y[w0+8]; yv[9]=y[w0+9];
            }

            float sx = 0.f, sy = 0.f, sxx = 0.f, syy = 0.f, sxy = 0.f;
            #pragma unroll
            for (int k = 0; k < WIN; k++) {
                float av = xv[k], bv = yv[k];
                sx += av; sy += bv;
                sxx = fmaf(av, av, sxx);
                syy = fmaf(bv, bv, syy);
                sxy = fmaf(av, bv, sxy);
            }
            #pragma unroll
            for (int j = 0; j < WPT; j++) {
                acc += ssim_from(sx, sy, sxx, syy, sxy, C1, C2);
                if (j < WPT - 1) {
                    float ao = xv[j], an = xv[j + WIN];
                    float bo = yv[j], bn = yv[j + WIN];
                    sx += an - ao;
                    sy += bn - bo;
                    sxx += fmaf(an, an, -(ao * ao));
                    syy += fmaf(bn, bn, -(bo * bo));
                    sxy += fmaf(an, bn, -(ao * bo));
                }
            }
        } else {   // last (partial) tile: scalar, guarded
            for (int j = 0; j < WPT; j++) {
                int w = w0 + j;
                if (w >= nw) break;
                float sx = 0.f, sy = 0.f, sxx = 0.f, syy = 0.f, sxy = 0.f;
                for (int k = 0; k < WIN; k++) {
                    float av = x[w + k], bv = y[w + k];
                    sx += av; sy += bv;
                    sxx = fmaf(av, av, sxx);
                    syy = fmaf(bv, bv, syy);
                    sxy = fmaf(av, bv, sxy);
                }
                acc += ssim_from(sx, sy, sxx, syy, sxy, C1, C2);
            }
        }
    }

    #pragma unroll
    for (int off = 32; off; off >>= 1) acc += __shfl_xor(acc, off);
    __shared__ float sm[4];
    if ((threadIdx.x & 63) == 0) sm[threadIdx.x >> 6] = acc;
    __syncthreads();
    if (threadIdx.x == 0)
        blockSums[blockIdx.x] = (sm[0] + sm[1]) + (sm[2] + sm[3]);
}

__global__ __launch_bounds__(BLK) void kfinal(const float* __restrict__ blockSums, int nb,
                                              float* __restrict__ out, int nw) {
    double s = 0.0;
    for (int i = threadIdx.x; i < nb; i += BLK) s += (double)blockSums[i];
    #pragma unroll
    for (int off = 32; off; off >>= 1) s += __shfl_xor(s, off);
    __shared__ double sm[4];
    if ((threadIdx.x & 63) == 0) sm[threadIdx.x >> 6] = s;
    __syncthreads();
    if (threadIdx.x == 0)
        out[0] = (float)(((sm[0] + sm[1]) + (sm[2] + sm[3])) / (double)nw);
}

extern "C" void kernel_launch(void* const* d_in, const int* in_sizes, int n_in,
                              void* d_out, int out_size, void* d_ws, size_t ws_size,
                              hipStream_t stream) {
    const float* x = (const float*)d_in[0];
    const float* y = (const float*)d_in[1];
    float* out = (float*)d_out;
    int n = in_sizes[0];
    int nw = n - (WIN - 1);
    int ntiles = (nw + TILE - 1) / TILE;

    float* wsf = (float*)d_ws;
    float* partMax   = wsf;          // 2048 floats
    float* finalMax  = wsf + 2048;   // 1 float
    float* blockSums = wsf + 4096;   // 2048 floats

    kmax_partial<<<MAXBLOCKS, BLK, 0, stream>>>(y, n, partMax);
    kmax_final<<<1, BLK, 0, stream>>>(partMax, MAXBLOCKS, finalMax);
    kssim<<<SSIM_BLOCKS, BLK, 0, stream>>>(x, y, finalMax, n, ntiles, blockSums);
    kfinal<<<1, BLK, 0, stream>>>(blockSums, SSIM_BLOCKS, out, nw);
}